// Round 1
// 567.112 us; speedup vs baseline: 1.2058x; 1.2058x over previous
//
#include <hip/hip_runtime.h>
#include <hip/hip_bf16.h>

// Show-Attend-Tell attention. B=128, P=196, E=2048, H=1024, A=1024.
// fp32 in / fp32 out (established round 6; passed absmax 1.95e-3).
// Round 8: GEMM rebuilt as pipelined 128x128 tile:
//   - k_wt pre-transposes W_enc -> bf16 Wt[A][E] in a 4 MB device global
//   - B staged via global_load_lds (linear LDS dest, XOR-swizzled source)
//   - A reg-staged prefetch (issue after barrier, consume after next barrier)
//   - double-buffered LDS, ONE raw s_barrier + vmcnt(0)/lgkmcnt(0) per K-step
// Intermediates inside d_out (fp32, 287232 elems total):
//   bytes [0      : 524288)  att2' fp32 [B][A]   (dead after GEMM)
//   bytes [524288 : 624640)  scores fp32 [M]     (dead after softmax)
//   elems [262144 : 287232)  alpha fp32 (final)
//   elems [0      : 262144)  context fp32 (final, written LAST by k_context)

#define B_   128
#define P_   196
#define E_   2048
#define H_   1024
#define A_   1024
#define M_   (B_ * P_)      // 25088
#define NKSTEP (E_ / 64)    // 32

typedef __bf16 bf16x8 __attribute__((ext_vector_type(8)));
typedef float f32x4 __attribute__((ext_vector_type(4)));

// W_enc transposed + converted once per launch: Wt[a][e] = (bf16)W_enc[e][a]
__device__ __bf16 g_wt[(size_t)A_ * E_];   // 4 MB module global

__device__ __forceinline__ bf16x8 cvt8r(const float4 a, const float4 b) {
    bf16x8 r;
    r[0] = (__bf16)a.x; r[1] = (__bf16)a.y; r[2] = (__bf16)a.z; r[3] = (__bf16)a.w;
    r[4] = (__bf16)b.x; r[5] = (__bf16)b.y; r[6] = (__bf16)b.z; r[7] = (__bf16)b.w;
    return r;
}

// async 16B global->LDS (lds dest must be wave-uniform; HW adds lane*16)
__device__ __forceinline__ void gl16(const void* g, void* l) {
    __builtin_amdgcn_global_load_lds(
        (const __attribute__((address_space(1))) unsigned int*)g,
        (__attribute__((address_space(3))) unsigned int*)l, 16, 0, 0);
}

// ---------------------------------------------------------------------------
// K0: Wt[a][e] = bf16(W_enc[e][a]).  64x64 tiles, one-shot (~5 us).
// ---------------------------------------------------------------------------
__global__ __launch_bounds__(256) void k_wt(const float* __restrict__ w) {
    __shared__ __bf16 tile[64][72];     // [a][e], stride 72 keeps 16B align
    const int t = threadIdx.x;
    const int a0 = blockIdx.x * 64, e0 = blockIdx.y * 64;
    const int er = t >> 2, c0 = (t & 3) * 16;
#pragma unroll
    for (int j = 0; j < 4; ++j) {
        const float4 v =
            *(const float4*)&w[(size_t)(e0 + er) * A_ + a0 + c0 + j * 4];
        tile[c0 + j * 4 + 0][er] = (__bf16)v.x;
        tile[c0 + j * 4 + 1][er] = (__bf16)v.y;
        tile[c0 + j * 4 + 2][er] = (__bf16)v.z;
        tile[c0 + j * 4 + 3][er] = (__bf16)v.w;
    }
    __syncthreads();
    const int ar = t >> 2, es0 = (t & 3) * 16;
    *(bf16x8*)&g_wt[(size_t)(a0 + ar) * E_ + e0 + es0] =
        *(const bf16x8*)&tile[ar][es0];
    *(bf16x8*)&g_wt[(size_t)(a0 + ar) * E_ + e0 + es0 + 8] =
        *(const bf16x8*)&tile[ar][es0 + 8];
}

// ---------------------------------------------------------------------------
// K1: zero scores; att2p[b][a] = b_enc[a]+b_dec[a]+sum_h dh[b][h]*W_dec[h][a]
// (unchanged from round 7)
// ---------------------------------------------------------------------------
__global__ __launch_bounds__(256) void k_att2(
    const float* __restrict__ dh, const float* __restrict__ wdec,
    const float* __restrict__ benc, const float* __restrict__ bdec,
    float* __restrict__ scores, float* __restrict__ att2p) {
    const int b = blockIdx.y;
    const int a0 = blockIdx.x * 128;
    const int t = threadIdx.x;
    const int bid = blockIdx.y * 8 + blockIdx.x;
    const int gi = bid * 256 + t;
    if (gi < M_) scores[gi] = 0.f;          // zero before GEMM's atomicAdd
    __shared__ float hs[H_];
    __shared__ float red[256];
    for (int i = t; i < H_; i += 256) hs[i] = dh[(size_t)b * H_ + i];
    __syncthreads();
    const int a = a0 + (t & 127);
    const int h0 = (t >> 7) * 512;
    float acc = 0.f;
#pragma unroll 8
    for (int h = 0; h < 512; ++h)
        acc += hs[h0 + h] * wdec[(size_t)(h0 + h) * A_ + a];
    red[t] = acc;
    __syncthreads();
    if (t < 128)
        att2p[(size_t)b * A_ + a0 + t] =
            red[t] + red[t + 128] + benc[a0 + t] + bdec[a0 + t];
}

// ---------------------------------------------------------------------------
// K2: fused GEMM(att1, bf16 MFMA) + bias + relu + W_full row-reduce ->
// atomicAdd into scores[M]. C-tile 128m x 128n, BK=64, dbuf LDS.
// 4 waves: wm=wave>>1, wn=wave&1; each wave 64x64 via 4x4 frags 16x16x32.
// B: global_load_lds direct, LDS linear [128 rows][64 k] bf16; the global
//    SOURCE address carries the inverse XOR swizzle (rule 21 / m173):
//    LDS[row][bib] holds element k where k*2 = bib ^ ((row&7)<<4).
//    Frag read therefore uses bib = (k*2) ^ ((row&7)<<4) -> 2-way banks.
// A: reg-staged fp32->bf16, pad-72 rows (2-way banks), prefetch issued right
//    after the barrier and written to the other buffer after compute.
// One raw s_barrier per K-step, preceded by vmcnt(0)+lgkmcnt(0); prefetched
// loads get a full compute phase to land, so the drain is near-free.
// ---------------------------------------------------------------------------
__global__ __launch_bounds__(256, 2) void k_gemm_scores(
    const float* __restrict__ Am,       // enc [M_][E_] fp32
    const float* __restrict__ att2p,    // [B_][A_] fp32
    const float* __restrict__ wfull,    // [A_] fp32
    float* __restrict__ scores) {       // [M_] fp32
    __shared__ __align__(16) __bf16 As[2][128 * 72];
    __shared__ __align__(16) __bf16 Bs[2][128 * 64];
    __shared__ float red[2][128];

    const int t = threadIdx.x;
    const int lane = t & 63;
    const int wave = t >> 6;
    const int wm = wave >> 1, wn = wave & 1;
    const int q = lane >> 4, r = lane & 15;
    const int bn = blockIdx.x, bm = blockIdx.y;
    const int m0 = bm * 128, n0 = bn * 128;

    // A staging: thread owns rows srow+{0,32,64,96}, 8 k-elems at sseg*8
    const int srow = t >> 3;            // 0..31
    const int sseg = t & 7;
    const float* aptr = Am + (size_t)(m0 + srow) * E_ + sseg * 8;
    // B staging: inst i stages rows i*32+(t>>3); source byte carries swizzle.
    const int bswz = (((t & 7) ^ ((t >> 3) & 7)) << 4);
    const char* wt0 =
        (const char*)g_wt + (size_t)(n0 + srow) * (E_ * 2) + bswz;
    char* bdst0 = (char*)&Bs[0][0] + wave * 1024;   // wave-uniform
    char* bdst1 = (char*)&Bs[1][0] + wave * 1024;

    f32x4 acc[4][4] = {};
    float4 areg[8];

    // ---- prologue: stage tile 0 into buffer 0 ----
#pragma unroll
    for (int i = 0; i < 4; ++i) {
        const float* p = aptr + (size_t)(i * 32) * E_;
        areg[2 * i]     = *(const float4*)p;
        areg[2 * i + 1] = *(const float4*)(p + 4);
    }
#pragma unroll
    for (int i = 0; i < 4; ++i)
        gl16(wt0 + (size_t)i * (32 * E_ * 2), bdst0 + i * 4096);
#pragma unroll
    for (int i = 0; i < 4; ++i)
        *(bf16x8*)&As[0][(srow + i * 32) * 72 + sseg * 8] =
            cvt8r(areg[2 * i], areg[2 * i + 1]);

    int cur = 0;
#pragma unroll 2
    for (int kt = 0; kt < NKSTEP; ++kt) {
        // buf[cur] ready once our own outstanding ops drain + all waves sync
        asm volatile("s_waitcnt vmcnt(0)" ::: "memory");
        asm volatile("s_waitcnt lgkmcnt(0)" ::: "memory");
        __builtin_amdgcn_s_barrier();

        const __bf16* AsC = &As[cur][0];
        __bf16* AsN = &As[cur ^ 1][0];
        const char* BsC = (const char*)&Bs[cur][0];
        char* bdstN = cur ? bdst0 : bdst1;
        const bool pf = (kt + 1 < NKSTEP);

        if (pf) {   // prefetch tile kt+1: A into regs, B into other buffer
            const float* pa = aptr + (size_t)(kt + 1) * 64;
#pragma unroll
            for (int i = 0; i < 4; ++i) {
                const float* p = pa + (size_t)(i * 32) * E_;
                areg[2 * i]     = *(const float4*)p;
                areg[2 * i + 1] = *(const float4*)(p + 4);
            }
#pragma unroll
            for (int i = 0; i < 4; ++i)
                gl16(wt0 + (size_t)i * (32 * E_ * 2) + (size_t)(kt + 1) * 128,
                     bdstN + i * 4096);
        }

        // compute tile kt (plain C++: compiler handles lgkm waits)
#pragma unroll
        for (int ks = 0; ks < 2; ++ks) {
            bf16x8 af[4], bfv[4];
#pragma unroll
            for (int f = 0; f < 4; ++f)
                af[f] = *(const bf16x8*)&AsC[(wm * 64 + f * 16 + r) * 72 +
                                             ks * 32 + q * 8];
#pragma unroll
            for (int f = 0; f < 4; ++f) {
                const int nf = wn * 64 + f * 16 + r;      // nf&7 == r&7
                bfv[f] = *(const bf16x8*)(BsC + nf * 128 +
                         ((ks * 64 + q * 16) ^ ((r & 7) << 4)));
            }
#pragma unroll
            for (int fm = 0; fm < 4; ++fm)
#pragma unroll
                for (int fn = 0; fn < 4; ++fn)
                    acc[fm][fn] = __builtin_amdgcn_mfma_f32_16x16x32_bf16(
                        af[fm], bfv[fn], acc[fm][fn], 0, 0, 0);
        }

        if (pf) {   // write prefetched A (compiler inserts vmcnt for areg)
#pragma unroll
            for (int i = 0; i < 4; ++i)
                *(bf16x8*)&AsN[(srow + i * 32) * 72 + sseg * 8] =
                    cvt8r(areg[2 * i], areg[2 * i + 1]);
        }
        cur ^= 1;
    }

    // Epilogue. C/D layout: col(n) = lane&15, row(m) = q*4 + reg.
    float psum[4][4];
    const float* wfb = wfull + n0 + wn * 64;
#pragma unroll
    for (int fm = 0; fm < 4; ++fm) {
#pragma unroll
        for (int i = 0; i < 4; ++i) {
            const int row_g = m0 + wm * 64 + fm * 16 + q * 4 + i;
            const unsigned bidx = (unsigned)row_g / 196u;
            const float* a2 = att2p + (size_t)bidx * A_ + n0 + wn * 64;
            float s = 0.f;
#pragma unroll
            for (int fn = 0; fn < 4; ++fn) {
                const int cl = fn * 16 + r;
                float v = acc[fm][fn][i] + a2[cl];
                v = fmaxf(v, 0.f);
                s += v * wfb[cl];
            }
            psum[fm][i] = s;
        }
    }
#pragma unroll
    for (int fm = 0; fm < 4; ++fm)
#pragma unroll
        for (int i = 0; i < 4; ++i) {
            float v = psum[fm][i];
            v += __shfl_xor(v, 1);
            v += __shfl_xor(v, 2);
            v += __shfl_xor(v, 4);
            v += __shfl_xor(v, 8);
            if (r == 0) red[wn][wm * 64 + fm * 16 + q * 4 + i] = v;
        }
    __syncthreads();
    if (t < 128) atomicAdd(&scores[m0 + t], red[0][t] + red[1][t]);
}

// ---------------------------------------------------------------------------
// K3: softmax over P=196 per batch; alpha (fp32) -> d_out elems [262144,...).
// ---------------------------------------------------------------------------
__global__ __launch_bounds__(256) void k_softmax(
    const float* __restrict__ scores, float* __restrict__ out) {
    const int b = blockIdx.x;
    const int t = threadIdx.x;
    __shared__ float sm[256];
    const bool act = t < P_;
    const float val = act ? scores[b * P_ + t] : 0.f;
    sm[t] = act ? val : -1e30f;
    __syncthreads();
    for (int off = 128; off > 0; off >>= 1) {
        if (t < off) sm[t] = fmaxf(sm[t], sm[t + off]);
        __syncthreads();
    }
    const float mx = sm[0];
    __syncthreads();
    const float e = act ? __expf(val - mx) : 0.f;
    sm[t] = e;
    __syncthreads();
    for (int off = 128; off > 0; off >>= 1) {
        if (t < off) sm[t] = sm[t] + sm[t + off];
        __syncthreads();
    }
    const float inv = 1.0f / sm[0];
    if (act) out[(size_t)B_ * E_ + b * P_ + t] = e * inv;
}

// ---------------------------------------------------------------------------
// K4: context[b][e] = sum_p alpha[b][p] * enc[b][p][e]  (all fp32)
// unroll 14 (196 = 14*14) for memory-level parallelism.
// ---------------------------------------------------------------------------
__global__ __launch_bounds__(256) void k_context(
    const float* __restrict__ enc, float* __restrict__ out) {
    const int b = blockIdx.y;
    const int e0 = blockIdx.x * 1024 + threadIdx.x * 4;
    __shared__ float al[P_];
    if (threadIdx.x < P_)
        al[threadIdx.x] = out[(size_t)B_ * E_ + b * P_ + threadIdx.x];
    __syncthreads();
    float ax = 0.f, ay = 0.f, az = 0.f, aw = 0.f;
    const float* base = enc + (size_t)b * P_ * E_ + e0;
#pragma unroll 14
    for (int p = 0; p < P_; ++p) {
        const float4 v = *(const float4*)(base + (size_t)p * E_);
        const float ap = al[p];
        ax += ap * v.x; ay += ap * v.y; az += ap * v.z; aw += ap * v.w;
    }
    float4 sv; sv.x = ax; sv.y = ay; sv.z = az; sv.w = aw;
    *(float4*)(out + (size_t)b * E_ + e0) = sv;
}

// ---------------------------------------------------------------------------
extern "C" void kernel_launch(void* const* d_in, const int* in_sizes, int n_in,
                              void* d_out, int out_size, void* d_ws,
                              size_t ws_size, hipStream_t stream) {
    const float* enc   = (const float*)d_in[0];
    const float* dh    = (const float*)d_in[1];
    const float* wenc  = (const float*)d_in[2];
    const float* benc  = (const float*)d_in[3];
    const float* wdec  = (const float*)d_in[4];
    const float* bdec  = (const float*)d_in[5];
    const float* wfull = (const float*)d_in[6];
    // d_in[7] = b_full: softmax shift-invariant, unused
    float* out = (float*)d_out;

    float* att2p  = out;                              // bytes [0, 524288)
    float* scores = (float*)((char*)d_out + 524288);  // bytes [524288, 624640)

    k_wt<<<dim3(A_ / 64, E_ / 64), 256, 0, stream>>>(wenc);
    k_att2<<<dim3(8, B_), 256, 0, stream>>>(dh, wdec, benc, bdec, scores,
                                            att2p);
    k_gemm_scores<<<dim3(8, M_ / 128), 256, 0, stream>>>(enc, att2p, wfull,
                                                         scores);
    k_softmax<<<B_, 256, 0, stream>>>(scores, out);
    k_context<<<dim3(2, B_), 256, 0, stream>>>(enc, out);
}

// Round 2
// 553.749 us; speedup vs baseline: 1.2349x; 1.0241x over previous
//
#include <hip/hip_runtime.h>
#include <hip/hip_bf16.h>

// Show-Attend-Tell attention. B=128, P=196, E=2048, H=1024, A=1024.
// fp32 in / fp32 out (established round 6; passed absmax 1.95e-3).
// Round 9:
//   - GEMM: XCD-aware bijective blockIdx swizzle (8 n-blocks sharing an
//     A-panel now run back-to-back on ONE XCD -> A panel is an L2 hit;
//     round-8 counters showed FETCH_SIZE 4x A = cross-XCD panel refetch).
//   - k_att2: re-grid (8 a-chunks x 16 b-groups), 8 batch rows per W_dec
//     load (was 1) -> 8x less W_dec effective traffic.
// Intermediates inside d_out (fp32, 287232 elems total):
//   bytes [0      : 524288)  att2' fp32 [B][A]   (dead after GEMM)
//   bytes [524288 : 624640)  scores fp32 [M]     (dead after softmax)
//   elems [262144 : 287232)  alpha fp32 (final)
//   elems [0      : 262144)  context fp32 (final, written LAST by k_context)

#define B_   128
#define P_   196
#define E_   2048
#define H_   1024
#define A_   1024
#define M_   (B_ * P_)      // 25088
#define NKSTEP (E_ / 64)    // 32

typedef __bf16 bf16x8 __attribute__((ext_vector_type(8)));
typedef float f32x4 __attribute__((ext_vector_type(4)));

// W_enc transposed + converted once per launch: Wt[a][e] = (bf16)W_enc[e][a]
__device__ __bf16 g_wt[(size_t)A_ * E_];   // 4 MB module global

__device__ __forceinline__ bf16x8 cvt8r(const float4 a, const float4 b) {
    bf16x8 r;
    r[0] = (__bf16)a.x; r[1] = (__bf16)a.y; r[2] = (__bf16)a.z; r[3] = (__bf16)a.w;
    r[4] = (__bf16)b.x; r[5] = (__bf16)b.y; r[6] = (__bf16)b.z; r[7] = (__bf16)b.w;
    return r;
}

// async 16B global->LDS (lds dest must be wave-uniform; HW adds lane*16)
__device__ __forceinline__ void gl16(const void* g, void* l) {
    __builtin_amdgcn_global_load_lds(
        (const __attribute__((address_space(1))) unsigned int*)g,
        (__attribute__((address_space(3))) unsigned int*)l, 16, 0, 0);
}

// ---------------------------------------------------------------------------
// K0: Wt[a][e] = bf16(W_enc[e][a]).  64x64 tiles, one-shot (~5 us).
// ---------------------------------------------------------------------------
__global__ __launch_bounds__(256) void k_wt(const float* __restrict__ w) {
    __shared__ __bf16 tile[64][72];     // [a][e], stride 72 keeps 16B align
    const int t = threadIdx.x;
    const int a0 = blockIdx.x * 64, e0 = blockIdx.y * 64;
    const int er = t >> 2, c0 = (t & 3) * 16;
#pragma unroll
    for (int j = 0; j < 4; ++j) {
        const float4 v =
            *(const float4*)&w[(size_t)(e0 + er) * A_ + a0 + c0 + j * 4];
        tile[c0 + j * 4 + 0][er] = (__bf16)v.x;
        tile[c0 + j * 4 + 1][er] = (__bf16)v.y;
        tile[c0 + j * 4 + 2][er] = (__bf16)v.z;
        tile[c0 + j * 4 + 3][er] = (__bf16)v.w;
    }
    __syncthreads();
    const int ar = t >> 2, es0 = (t & 3) * 16;
    *(bf16x8*)&g_wt[(size_t)(a0 + ar) * E_ + e0 + es0] =
        *(const bf16x8*)&tile[ar][es0];
    *(bf16x8*)&g_wt[(size_t)(a0 + ar) * E_ + e0 + es0 + 8] =
        *(const bf16x8*)&tile[ar][es0 + 8];
}

// ---------------------------------------------------------------------------
// K1: zero scores; att2p[b][a] = b_enc[a]+b_dec[a]+sum_h dh[b][h]*W_dec[h][a]
// Round 9: grid (8 a-chunks, 16 b-groups of 8). Each W_dec load feeds 8
// batch rows (8 FMA/load). W_dec effective traffic 512 MB -> 64 MB.
// ---------------------------------------------------------------------------
__global__ __launch_bounds__(256) void k_att2(
    const float* __restrict__ dh, const float* __restrict__ wdec,
    const float* __restrict__ benc, const float* __restrict__ bdec,
    float* __restrict__ scores, float* __restrict__ att2p) {
    const int t = threadIdx.x;
    const int a0 = blockIdx.x * 128;
    const int b0 = blockIdx.y * 8;
    const int bid = blockIdx.y * 8 + blockIdx.x;     // 0..127
    const int gi = bid * 256 + t;
    if (gi < M_) scores[gi] = 0.f;          // zero before GEMM's atomicAdd
    __shared__ float hs[8][H_];             // 32 KB
    __shared__ float red[256][8];           // 8 KB
    for (int i = t; i < 8 * H_; i += 256)
        hs[i >> 10][i & 1023] = dh[(size_t)(b0 + (i >> 10)) * H_ + (i & 1023)];
    __syncthreads();
    const int a = a0 + (t & 127);
    const int h0 = (t >> 7) * 512;
    float acc[8] = {};
#pragma unroll 4
    for (int h = 0; h < 512; ++h) {
        const float w = wdec[(size_t)(h0 + h) * A_ + a];
#pragma unroll
        for (int j = 0; j < 8; ++j) acc[j] += hs[j][h0 + h] * w;
    }
#pragma unroll
    for (int j = 0; j < 8; ++j) red[t][j] = acc[j];
    __syncthreads();
    if (t < 128) {
        const float bb = benc[a0 + t] + bdec[a0 + t];
#pragma unroll
        for (int j = 0; j < 8; ++j)
            att2p[(size_t)(b0 + j) * A_ + a0 + t] =
                red[t][j] + red[t + 128][j] + bb;
    }
}

// ---------------------------------------------------------------------------
// K2: fused GEMM(att1, bf16 MFMA) + bias + relu + W_full row-reduce ->
// atomicAdd into scores[M]. C-tile 128m x 128n, BK=64, dbuf LDS.
// 4 waves: wm=wave>>1, wn=wave&1; each wave 64x64 via 4x4 frags 16x16x32.
// B: global_load_lds direct, LDS linear [128 rows][64 k] bf16; the global
//    SOURCE address carries the inverse XOR swizzle (rule 21 / m173):
//    LDS[row][bib] holds element k where k*2 = bib ^ ((row&7)<<4).
//    Frag read therefore uses bib = (k*2) ^ ((row&7)<<4) -> 2-way banks.
// A: reg-staged fp32->bf16, pad-72 rows (2-way banks), prefetch issued right
//    after the barrier and written to the other buffer after compute.
// One raw s_barrier per K-step, preceded by vmcnt(0)+lgkmcnt(0).
// Round 9: XCD swizzle — logical id L = (orig&7)*196 + orig/8 (bijective,
// nwg=1568=8*196). The 8 n-blocks of an m-panel (L=bm*8..bm*8+7) become
// back-to-back dispatches on ONE XCD -> A-panel L2 reuse.
// ---------------------------------------------------------------------------
__global__ __launch_bounds__(256, 2) void k_gemm_scores(
    const float* __restrict__ Am,       // enc [M_][E_] fp32
    const float* __restrict__ att2p,    // [B_][A_] fp32
    const float* __restrict__ wfull,    // [A_] fp32
    float* __restrict__ scores) {       // [M_] fp32
    __shared__ __align__(16) __bf16 As[2][128 * 72];
    __shared__ __align__(16) __bf16 Bs[2][128 * 64];
    __shared__ float red[2][128];

    const int t = threadIdx.x;
    const int lane = t & 63;
    const int wave = t >> 6;
    const int wm = wave >> 1, wn = wave & 1;
    const int q = lane >> 4, r = lane & 15;
    const int orig = blockIdx.y * 8 + blockIdx.x;      // 0..1567
    const int L = (orig & 7) * (M_ / 128) + (orig >> 3);
    const int bn = L & 7, bm = L >> 3;
    const int m0 = bm * 128, n0 = bn * 128;

    // A staging: thread owns rows srow+{0,32,64,96}, 8 k-elems at sseg*8
    const int srow = t >> 3;            // 0..31
    const int sseg = t & 7;
    const float* aptr = Am + (size_t)(m0 + srow) * E_ + sseg * 8;
    // B staging: inst i stages rows i*32+(t>>3); source byte carries swizzle.
    const int bswz = (((t & 7) ^ ((t >> 3) & 7)) << 4);
    const char* wt0 =
        (const char*)g_wt + (size_t)(n0 + srow) * (E_ * 2) + bswz;
    char* bdst0 = (char*)&Bs[0][0] + wave * 1024;   // wave-uniform
    char* bdst1 = (char*)&Bs[1][0] + wave * 1024;

    f32x4 acc[4][4] = {};
    float4 areg[8];

    // ---- prologue: stage tile 0 into buffer 0 ----
#pragma unroll
    for (int i = 0; i < 4; ++i) {
        const float* p = aptr + (size_t)(i * 32) * E_;
        areg[2 * i]     = *(const float4*)p;
        areg[2 * i + 1] = *(const float4*)(p + 4);
    }
#pragma unroll
    for (int i = 0; i < 4; ++i)
        gl16(wt0 + (size_t)i * (32 * E_ * 2), bdst0 + i * 4096);
#pragma unroll
    for (int i = 0; i < 4; ++i)
        *(bf16x8*)&As[0][(srow + i * 32) * 72 + sseg * 8] =
            cvt8r(areg[2 * i], areg[2 * i + 1]);

    int cur = 0;
#pragma unroll 2
    for (int kt = 0; kt < NKSTEP; ++kt) {
        // buf[cur] ready once our own outstanding ops drain + all waves sync
        asm volatile("s_waitcnt vmcnt(0)" ::: "memory");
        asm volatile("s_waitcnt lgkmcnt(0)" ::: "memory");
        __builtin_amdgcn_s_barrier();

        const __bf16* AsC = &As[cur][0];
        __bf16* AsN = &As[cur ^ 1][0];
        const char* BsC = (const char*)&Bs[cur][0];
        char* bdstN = cur ? bdst0 : bdst1;
        const bool pf = (kt + 1 < NKSTEP);

        if (pf) {   // prefetch tile kt+1: A into regs, B into other buffer
            const float* pa = aptr + (size_t)(kt + 1) * 64;
#pragma unroll
            for (int i = 0; i < 4; ++i) {
                const float* p = pa + (size_t)(i * 32) * E_;
                areg[2 * i]     = *(const float4*)p;
                areg[2 * i + 1] = *(const float4*)(p + 4);
            }
#pragma unroll
            for (int i = 0; i < 4; ++i)
                gl16(wt0 + (size_t)i * (32 * E_ * 2) + (size_t)(kt + 1) * 128,
                     bdstN + i * 4096);
        }

        // compute tile kt (plain C++: compiler handles lgkm waits)
#pragma unroll
        for (int ks = 0; ks < 2; ++ks) {
            bf16x8 af[4], bfv[4];
#pragma unroll
            for (int f = 0; f < 4; ++f)
                af[f] = *(const bf16x8*)&AsC[(wm * 64 + f * 16 + r) * 72 +
                                             ks * 32 + q * 8];
#pragma unroll
            for (int f = 0; f < 4; ++f) {
                const int nf = wn * 64 + f * 16 + r;      // nf&7 == r&7
                bfv[f] = *(const bf16x8*)(BsC + nf * 128 +
                         ((ks * 64 + q * 16) ^ ((r & 7) << 4)));
            }
#pragma unroll
            for (int fm = 0; fm < 4; ++fm)
#pragma unroll
                for (int fn = 0; fn < 4; ++fn)
                    acc[fm][fn] = __builtin_amdgcn_mfma_f32_16x16x32_bf16(
                        af[fm], bfv[fn], acc[fm][fn], 0, 0, 0);
        }

        if (pf) {   // write prefetched A (compiler inserts vmcnt for areg)
#pragma unroll
            for (int i = 0; i < 4; ++i)
                *(bf16x8*)&AsN[(srow + i * 32) * 72 + sseg * 8] =
                    cvt8r(areg[2 * i], areg[2 * i + 1]);
        }
        cur ^= 1;
    }

    // Epilogue. C/D layout: col(n) = lane&15, row(m) = q*4 + reg.
    float psum[4][4];
    const float* wfb = wfull + n0 + wn * 64;
#pragma unroll
    for (int fm = 0; fm < 4; ++fm) {
#pragma unroll
        for (int i = 0; i < 4; ++i) {
            const int row_g = m0 + wm * 64 + fm * 16 + q * 4 + i;
            const unsigned bidx = (unsigned)row_g / 196u;
            const float* a2 = att2p + (size_t)bidx * A_ + n0 + wn * 64;
            float s = 0.f;
#pragma unroll
            for (int fn = 0; fn < 4; ++fn) {
                const int cl = fn * 16 + r;
                float v = acc[fm][fn][i] + a2[cl];
                v = fmaxf(v, 0.f);
                s += v * wfb[cl];
            }
            psum[fm][i] = s;
        }
    }
#pragma unroll
    for (int fm = 0; fm < 4; ++fm)
#pragma unroll
        for (int i = 0; i < 4; ++i) {
            float v = psum[fm][i];
            v += __shfl_xor(v, 1);
            v += __shfl_xor(v, 2);
            v += __shfl_xor(v, 4);
            v += __shfl_xor(v, 8);
            if (r == 0) red[wn][wm * 64 + fm * 16 + q * 4 + i] = v;
        }
    __syncthreads();
    if (t < 128) atomicAdd(&scores[m0 + t], red[0][t] + red[1][t]);
}

// ---------------------------------------------------------------------------
// K3: softmax over P=196 per batch; alpha (fp32) -> d_out elems [262144,...).
// ---------------------------------------------------------------------------
__global__ __launch_bounds__(256) void k_softmax(
    const float* __restrict__ scores, float* __restrict__ out) {
    const int b = blockIdx.x;
    const int t = threadIdx.x;
    __shared__ float sm[256];
    const bool act = t < P_;
    const float val = act ? scores[b * P_ + t] : 0.f;
    sm[t] = act ? val : -1e30f;
    __syncthreads();
    for (int off = 128; off > 0; off >>= 1) {
        if (t < off) sm[t] = fmaxf(sm[t], sm[t + off]);
        __syncthreads();
    }
    const float mx = sm[0];
    __syncthreads();
    const float e = act ? __expf(val - mx) : 0.f;
    sm[t] = e;
    __syncthreads();
    for (int off = 128; off > 0; off >>= 1) {
        if (t < off) sm[t] = sm[t] + sm[t + off];
        __syncthreads();
    }
    const float inv = 1.0f / sm[0];
    if (act) out[(size_t)B_ * E_ + b * P_ + t] = e * inv;
}

// ---------------------------------------------------------------------------
// K4: context[b][e] = sum_p alpha[b][p] * enc[b][p][e]  (all fp32)
// unroll 14 (196 = 14*14) for memory-level parallelism.
// ---------------------------------------------------------------------------
__global__ __launch_bounds__(256) void k_context(
    const float* __restrict__ enc, float* __restrict__ out) {
    const int b = blockIdx.y;
    const int e0 = blockIdx.x * 1024 + threadIdx.x * 4;
    __shared__ float al[P_];
    if (threadIdx.x < P_)
        al[threadIdx.x] = out[(size_t)B_ * E_ + b * P_ + threadIdx.x];
    __syncthreads();
    float ax = 0.f, ay = 0.f, az = 0.f, aw = 0.f;
    const float* base = enc + (size_t)b * P_ * E_ + e0;
#pragma unroll 14
    for (int p = 0; p < P_; ++p) {
        const float4 v = *(const float4*)(base + (size_t)p * E_);
        const float ap = al[p];
        ax += ap * v.x; ay += ap * v.y; az += ap * v.z; aw += ap * v.w;
    }
    float4 sv; sv.x = ax; sv.y = ay; sv.z = az; sv.w = aw;
    *(float4*)(out + (size_t)b * E_ + e0) = sv;
}

// ---------------------------------------------------------------------------
extern "C" void kernel_launch(void* const* d_in, const int* in_sizes, int n_in,
                              void* d_out, int out_size, void* d_ws,
                              size_t ws_size, hipStream_t stream) {
    const float* enc   = (const float*)d_in[0];
    const float* dh    = (const float*)d_in[1];
    const float* wenc  = (const float*)d_in[2];
    const float* benc  = (const float*)d_in[3];
    const float* wdec  = (const float*)d_in[4];
    const float* bdec  = (const float*)d_in[5];
    const float* wfull = (const float*)d_in[6];
    // d_in[7] = b_full: softmax shift-invariant, unused
    float* out = (float*)d_out;

    float* att2p  = out;                              // bytes [0, 524288)
    float* scores = (float*)((char*)d_out + 524288);  // bytes [524288, 624640)

    k_wt<<<dim3(A_ / 64, E_ / 64), 256, 0, stream>>>(wenc);
    k_att2<<<dim3(8, 16), 256, 0, stream>>>(dh, wdec, benc, bdec, scores,
                                            att2p);
    k_gemm_scores<<<dim3(8, M_ / 128), 256, 0, stream>>>(enc, att2p, wfull,
                                                         scores);
    k_softmax<<<B_, 256, 0, stream>>>(scores, out);
    k_context<<<dim3(2, B_), 256, 0, stream>>>(enc, out);
}